// Round 2
// baseline (251.305 us; speedup 1.0000x reference)
//
#include <hip/hip_runtime.h>
#include <hip/hip_bf16.h>
#include <cstdint>
#include <cstddef>

// ---------------- types ----------------
typedef __bf16 bf16x8 __attribute__((ext_vector_type(8)));
typedef float f32x4 __attribute__((ext_vector_type(4)));
typedef float f32x16 __attribute__((ext_vector_type(16)));
typedef unsigned short u16x8 __attribute__((ext_vector_type(8)));
typedef unsigned short u16x4 __attribute__((ext_vector_type(4)));

#define S_LEN 2048
#define DMODEL 2048
#define NHEADS 16
#define HD 128

__device__ inline unsigned short f2bf(float f) {
  union { float f; unsigned int u; } v; v.f = f;
  unsigned int r = (v.u + 0x7fffu + ((v.u >> 16) & 1u)) >> 16;
  return (unsigned short)r;
}

// async global->LDS, 16B per lane; LDS dest = wave-uniform base + lane*16
__device__ __forceinline__ void gload16(const unsigned short* g,
                                        unsigned short* lds) {
  __builtin_amdgcn_global_load_lds(
      (const __attribute__((address_space(1))) void*)g,
      (__attribute__((address_space(3))) void*)lds, 16, 0, 0);
}

// ---------------- fused cast fp32 -> bf16 (all 5 matrices, 1 dispatch) -----
__global__ void cast_all(const float* __restrict__ x, const float* __restrict__ wq,
                         const float* __restrict__ wk, const float* __restrict__ wv,
                         const float* __restrict__ wo,
                         unsigned short* __restrict__ out, float qscale) {
  const int b = blockIdx.x;
  const int seg = b >> 12;                       // 4096 blocks per segment
  const int i = ((b & 4095) * 256 + threadIdx.x) * 4;
  const float* src = seg == 0 ? x : seg == 1 ? wq : seg == 2 ? wk
                   : seg == 3 ? wv : wo;
  const float scale = (seg == 1) ? qscale : 1.0f;
  unsigned short* dst = out + (size_t)seg * ((size_t)S_LEN * DMODEL);
  float4 v = *(const float4*)(src + i);
  u16x4 o;
  o.x = f2bf(v.x * scale); o.y = f2bf(v.y * scale);
  o.z = f2bf(v.z * scale); o.w = f2bf(v.w * scale);
  *(u16x4*)(dst + i) = o;
}

// ---------------- GEMM core: C[M,N] = A[M,K] * B[N,K]^T (bf16, fp32 acc) ---
// BK=64, XOR column-chunk swizzle staging (see round-6 notes).
// MODE 1: bf16 out   MODE 2: bf16 out transposed (C^T)
template <int MODE>
__device__ __forceinline__ void gemm_core64(
    const unsigned short* __restrict__ A, const unsigned short* __restrict__ B,
    unsigned short* __restrict__ Cb,
    int M, int N, int K, int m0, int n0,
    unsigned short* As, unsigned short* Bs) {
  constexpr int BK = 64;
  const int tid = threadIdx.x;
  const int wave = tid >> 6, lane = tid & 63;
  const int lg = lane >> 4, lr = lane & 15;
  const int rw = (wave >> 1) * 64;
  const int cw = (wave & 1) * 64;
  const int swz = lr & 7;

  const unsigned short* Ap[4];
  const unsigned short* Bp[4];
  unsigned short *as[4], *bs[4];
#pragma unroll
  for (int j = 0; j < 4; j++) {
    const int cc = j * 256 + tid;
    const int row = cc >> 3;
    const int col8 = (cc & 7) ^ (row & 7);       // XOR swizzle
    Ap[j] = A + (size_t)(m0 + row) * K + col8 * 8;
    Bp[j] = B + (size_t)(n0 + row) * K + col8 * 8;
    as[j] = As + j * 2048 + wave * 512;
    bs[j] = Bs + j * 2048 + wave * 512;
  }

  f32x4 acc[4][4];
#pragma unroll
  for (int i = 0; i < 4; i++)
#pragma unroll
    for (int j = 0; j < 4; j++) acc[i][j] = (f32x4){0.f, 0.f, 0.f, 0.f};

  const int nk = K / BK;
  for (int kt = 0; kt < nk; ++kt) {
    const int ko = kt * BK;
    __syncthreads();
#pragma unroll
    for (int j = 0; j < 4; j++) {
      gload16(Ap[j] + ko, as[j]);
      gload16(Bp[j] + ko, bs[j]);
    }
    __syncthreads();

#pragma unroll
    for (int kk = 0; kk < 2; kk++) {
      bf16x8 af[4], bfr[4];
#pragma unroll
      for (int mt = 0; mt < 4; mt++)
        af[mt] = *(const bf16x8*)(As + (rw + mt * 16 + lr) * 64 +
                                  (((kk * 4 + lg) ^ swz) * 8));
#pragma unroll
      for (int nt = 0; nt < 4; nt++)
        bfr[nt] = *(const bf16x8*)(Bs + (cw + nt * 16 + lr) * 64 +
                                   (((kk * 4 + lg) ^ swz) * 8));
#pragma unroll
      for (int mt = 0; mt < 4; mt++)
#pragma unroll
        for (int nt = 0; nt < 4; nt++)
          acc[mt][nt] = __builtin_amdgcn_mfma_f32_16x16x32_bf16(
              af[mt], bfr[nt], acc[mt][nt], 0, 0, 0);
    }
  }

#pragma unroll
  for (int mt = 0; mt < 4; mt++)
#pragma unroll
    for (int nt = 0; nt < 4; nt++) {
      const int col = n0 + cw + nt * 16 + lr;
#pragma unroll
      for (int r = 0; r < 4; r++) {
        const int row = m0 + rw + mt * 16 + lg * 4 + r;
        const float v = acc[mt][nt][r];
        if (MODE == 1) Cb[(size_t)row * N + col] = f2bf(v);
        else Cb[(size_t)col * M + row] = f2bf(v);
      }
    }
}

// fused Q/K/V projection: grid (48, 16); blockIdx.x>>4 selects weight/output
__global__ __launch_bounds__(256, 2) void gemm_qkv(
    const unsigned short* __restrict__ xb, const unsigned short* __restrict__ wqb,
    const unsigned short* __restrict__ wkb, const unsigned short* __restrict__ wvb,
    unsigned short* __restrict__ qb, unsigned short* __restrict__ kb,
    unsigned short* __restrict__ vTb) {
  __shared__ unsigned short As[128 * 64];
  __shared__ unsigned short Bs[128 * 64];
  const int which = blockIdx.x >> 4;             // block-uniform
  const int n0 = (blockIdx.x & 15) * 128;
  const int m0 = blockIdx.y * 128;
  if (which == 0)
    gemm_core64<1>(xb, wqb, qb, S_LEN, DMODEL, DMODEL, m0, n0, As, Bs);
  else if (which == 1)
    gemm_core64<1>(xb, wkb, kb, S_LEN, DMODEL, DMODEL, m0, n0, As, Bs);
  else
    gemm_core64<2>(xb, wvb, vTb, S_LEN, DMODEL, DMODEL, m0, n0, As, Bs);
}

// ---------------- O-projection GEMM, 64x128 tile, BK=128, fp32 out --------
// 32 MFMA per barrier pair; 48KB LDS -> 2 blocks/CU kept (grid 512 = 2/CU).
__global__ __launch_bounds__(256, 2) void gemm_bt64(
    const unsigned short* __restrict__ A, const unsigned short* __restrict__ B,
    float* __restrict__ Cf, int M, int N, int K) {
  constexpr int BK = 128;
  __shared__ unsigned short As[64 * 128];
  __shared__ unsigned short Bs[128 * 128];
  const int tid = threadIdx.x;
  const int wave = tid >> 6, lane = tid & 63;
  const int lg = lane >> 4, lr = lane & 15;
  const int rw = (wave >> 1) * 32;
  const int cw = (wave & 1) * 64;
  const int m0 = blockIdx.y * 64, n0 = blockIdx.x * 128;
  const int swz = lr & 7;

  // chunks of 8 elems: A 64x16=1024 (4 sets), B 128x16=2048 (8 sets)
  const unsigned short* Ap[4];
  const unsigned short* Bp[8];
  unsigned short *as[4], *bs[8];
#pragma unroll
  for (int j = 0; j < 4; j++) {
    const int cc = j * 256 + tid;
    const int row = cc >> 4;
    const int col16 = (cc & 15) ^ (row & 7);
    Ap[j] = A + (size_t)(m0 + row) * K + col16 * 8;
    as[j] = As + j * 2048 + wave * 512;
  }
#pragma unroll
  for (int j = 0; j < 8; j++) {
    const int cc = j * 256 + tid;
    const int row = cc >> 4;
    const int col16 = (cc & 15) ^ (row & 7);
    Bp[j] = B + (size_t)(n0 + row) * K + col16 * 8;
    bs[j] = Bs + j * 2048 + wave * 512;
  }

  f32x4 acc[2][4];
#pragma unroll
  for (int i = 0; i < 2; i++)
#pragma unroll
    for (int j = 0; j < 4; j++) acc[i][j] = (f32x4){0.f, 0.f, 0.f, 0.f};

  const int nk = K / BK;
  for (int kt = 0; kt < nk; ++kt) {
    const int ko = kt * BK;
    __syncthreads();
#pragma unroll
    for (int j = 0; j < 4; j++) gload16(Ap[j] + ko, as[j]);
#pragma unroll
    for (int j = 0; j < 8; j++) gload16(Bp[j] + ko, bs[j]);
    __syncthreads();

#pragma unroll
    for (int kk = 0; kk < 4; kk++) {
      bf16x8 af[2], bfr[4];
#pragma unroll
      for (int mt = 0; mt < 2; mt++)
        af[mt] = *(const bf16x8*)(As + (rw + mt * 16 + lr) * 128 +
                                  (((kk * 4 + lg) ^ swz) * 8));
#pragma unroll
      for (int nt = 0; nt < 4; nt++)
        bfr[nt] = *(const bf16x8*)(Bs + (cw + nt * 16 + lr) * 128 +
                                   (((kk * 4 + lg) ^ swz) * 8));
#pragma unroll
      for (int mt = 0; mt < 2; mt++)
#pragma unroll
        for (int nt = 0; nt < 4; nt++)
          acc[mt][nt] = __builtin_amdgcn_mfma_f32_16x16x32_bf16(
              af[mt], bfr[nt], acc[mt][nt], 0, 0, 0);
    }
  }

#pragma unroll
  for (int mt = 0; mt < 2; mt++)
#pragma unroll
    for (int nt = 0; nt < 4; nt++) {
      const int col = n0 + cw + nt * 16 + lr;
#pragma unroll
      for (int r = 0; r < 4; r++) {
        const int row = m0 + rw + mt * 16 + lg * 4 + r;
        Cf[(size_t)row * N + col] = acc[mt][nt][r];
      }
    }
}

// ---------------- flash attention, transposed 32x32-MFMA, 2 barriers/tile --
// S^T = K*Q^T (A=Ks dbuf, B=Q regs); P = exp2(S^T); O^T = V^T*P^T.
// Per tile: write Vt(t); prefetch t+1; S^T on Ks[t&1]; exp2+P-store;
// write Ks[(t+1)&1]; bar1 (P/Vt/Ks-next visible); PV; bar2 (WAR Vt/Ps).
// Every cross-wave write->read and read->overwrite pair crosses >=1 barrier.
//
// Round-7 changes (latency attack; MfmaUtil was 24.6%):
//  * S^T accumulation split into 2 independent 4-deep MFMA chains
//    (sacc0/sacc1, combined with one fp32 vector add) -- halves the
//    dependent-MFMA critical path that 2 waves/SIMD can't hide.
//  * All K fragments hoisted into regs before the S^T MFMA cluster;
//    all P/V fragments hoisted before the PV cluster -> pure-register
//    MFMA clusters.
//  * s_setprio(1) around both MFMA clusters (T5: +4-7% attn, m191).
//  * lsum kept in 4 partial accumulators (breaks 16-add serial chain).
__global__ __launch_bounds__(256, 2) void attn_kernel(
    const unsigned short* __restrict__ q, const unsigned short* __restrict__ k,
    const unsigned short* __restrict__ vT, unsigned short* __restrict__ o) {
  constexpr int KT = 64;
  __shared__ unsigned short Ks[2][64 * 136];  // dbuf [key][dim 128 + 8 pad]
  __shared__ unsigned short Vt[128 * 72];     // [dim][key + 8 pad]
  __shared__ unsigned short Ps[64 * 72];      // [query][key + 8 pad]
  __shared__ float Lred[4][32];

  const int tid = threadIdx.x;
  const int w = tid >> 6, lane = tid & 63;
  const int l32 = lane & 31, lh = lane >> 5;
  const int qh = w >> 1;     // query half (S^T and PV)
  const int kh = w & 1;      // key half (S^T) == dim half (PV)
  const int h = blockIdx.y;
  const int q0 = blockIdx.x * 64;

  // Q as B-fragments in registers: B[k=d][n=q]
  bf16x8 qf[8];
#pragma unroll
  for (int ks = 0; ks < 8; ks++)
    qf[ks] = *(const bf16x8*)(q + (size_t)(q0 + qh * 32 + l32) * DMODEL +
                              h * HD + ks * 16 + lh * 8);

  f32x16 Oacc[2];
#pragma unroll
  for (int mt = 0; mt < 2; mt++)
#pragma unroll
    for (int j = 0; j < 16; j++) Oacc[mt][j] = 0.f;
  f32x4 lsumv = (f32x4){0.f, 0.f, 0.f, 0.f};   // 4 partial l accumulators

  // staging coordinates
  int krow[4], kcg[4], vrow[4], vcg[4];
#pragma unroll
  for (int i = 0; i < 4; i++) {
    const int c = i * 256 + tid;
    krow[i] = c >> 4; kcg[i] = c & 15;
    vrow[i] = c >> 3; vcg[i] = c & 7;
  }

  // prologue: tile 0 into regs; Ks[0] written; Vt written at loop top
  u16x8 kreg[4], vreg[4];
#pragma unroll
  for (int i = 0; i < 4; i++) {
    kreg[i] = *(const u16x8*)(k + (size_t)(krow[i]) * DMODEL + h * HD + kcg[i] * 8);
    vreg[i] = *(const u16x8*)(vT + (size_t)(h * HD + vrow[i]) * S_LEN + vcg[i] * 8);
  }
#pragma unroll
  for (int i = 0; i < 4; i++)
    *(u16x8*)(Ks[0] + krow[i] * 136 + kcg[i] * 8) = kreg[i];
  __syncthreads();   // Ks[0] visible (acts as bar2 of tile -1)

  constexpr int NT = S_LEN / KT;
  for (int kt = 0; kt < NT; ++kt) {
    // write Vt(t) -- PV(t-1) done per bar2
#pragma unroll
    for (int i = 0; i < 4; i++)
      *(u16x8*)(Vt + vrow[i] * 72 + vcg[i] * 8) = vreg[i];

    // prefetch tile t+1 into regs (covers S^T + exp2 before Ks write)
    if (kt + 1 < NT) {
      const int kbase = (kt + 1) * KT;
#pragma unroll
      for (int i = 0; i < 4; i++) {
        kreg[i] = *(const u16x8*)(k + (size_t)(kbase + krow[i]) * DMODEL +
                                  h * HD + kcg[i] * 8);
        vreg[i] = *(const u16x8*)(vT + (size_t)(h * HD + vrow[i]) * S_LEN +
                                  kbase + vcg[i] * 8);
      }
    }

    // S^T = K * Q^T on Ks[kt&1] -- hoisted K frags, 2 independent chains
    const unsigned short* Kcur = Ks[kt & 1];
    bf16x8 kf[8];
#pragma unroll
    for (int ks = 0; ks < 8; ks++)
      kf[ks] = *(const bf16x8*)(Kcur + (kh * 32 + l32) * 136 + ks * 16 + lh * 8);

    f32x16 sacc0, sacc1;
#pragma unroll
    for (int j = 0; j < 16; j++) { sacc0[j] = 0.f; sacc1[j] = 0.f; }
    __builtin_amdgcn_s_setprio(1);
#pragma unroll
    for (int ks = 0; ks < 4; ks++) {
      sacc0 = __builtin_amdgcn_mfma_f32_32x32x16_bf16(kf[ks], qf[ks], sacc0,
                                                      0, 0, 0);
      sacc1 = __builtin_amdgcn_mfma_f32_32x32x16_bf16(kf[ks + 4], qf[ks + 4],
                                                      sacc1, 0, 0, 0);
    }
    __builtin_amdgcn_s_setprio(0);
    const f32x16 sacc = sacc0 + sacc1;

    // P = exp2(S^T); pack 4 consecutive keys -> b64 into Ps[q][key]
#pragma unroll
    for (int rq = 0; rq < 4; rq++) {
      u16x4 pk;
#pragma unroll
      for (int ri = 0; ri < 4; ri++) {
        const float p = __builtin_amdgcn_exp2f(sacc[rq * 4 + ri]);
        lsumv[ri] += p;
        union { float f; unsigned int u; } cv; cv.f = p;
        pk[ri] = (unsigned short)(cv.u >> 16);
      }
      *(u16x4*)(Ps + (qh * 32 + l32) * 72 + kh * 32 + rq * 8 + lh * 4) = pk;
    }

    // write Ks[(t+1)&1] (other buffer: last reads were S^T(t-1), pre-bar1(t-1))
    if (kt + 1 < NT) {
#pragma unroll
      for (int i = 0; i < 4; i++)
        *(u16x8*)(Ks[(kt + 1) & 1] + krow[i] * 136 + kcg[i] * 8) = kreg[i];
    }
    __syncthreads();   // bar1: P, Vt, Ks-next visible

    // O^T += V^T * P^T -- hoisted frags, pure-register MFMA cluster
    bf16x8 pfr[4], vf[2][4];
#pragma unroll
    for (int ks2 = 0; ks2 < 4; ks2++)
      pfr[ks2] =
          *(const bf16x8*)(Ps + (qh * 32 + l32) * 72 + ks2 * 16 + lh * 8);
#pragma unroll
    for (int ks2 = 0; ks2 < 4; ks2++)
#pragma unroll
      for (int mt = 0; mt < 2; mt++)
        vf[mt][ks2] = *(const bf16x8*)(
            Vt + (kh * 64 + mt * 32 + l32) * 72 + ks2 * 16 + lh * 8);

    __builtin_amdgcn_s_setprio(1);
#pragma unroll
    for (int ks2 = 0; ks2 < 4; ks2++)
#pragma unroll
      for (int mt = 0; mt < 2; mt++)
        Oacc[mt] = __builtin_amdgcn_mfma_f32_32x32x16_bf16(
            vf[mt][ks2], pfr[ks2], Oacc[mt], 0, 0, 0);
    __builtin_amdgcn_s_setprio(0);
    __syncthreads();   // bar2: PV done -> Vt/Ps writable next tile
  }

  // ---- epilogue: l reduction (lane^32, then cross-wave pair via LDS) ----
  float lsum = (lsumv[0] + lsumv[1]) + (lsumv[2] + lsumv[3]);
  lsum += __shfl_xor(lsum, 32);
  if (lh == 0) Lred[w][l32] = lsum;
  __syncthreads();
  const float ltot = Lred[qh * 2][l32] + Lred[qh * 2 + 1][l32];
  const float inv = 1.0f / ltot;

  // O^T -> O transpose through LDS (reuse Ks[0] as [64 q][136]); coalesced out
#pragma unroll
  for (int mt = 0; mt < 2; mt++)
#pragma unroll
    for (int rq = 0; rq < 4; rq++) {
      u16x4 pk;
#pragma unroll
      for (int ri = 0; ri < 4; ri++)
        pk[ri] = f2bf(Oacc[mt][rq * 4 + ri] * inv);
      *(u16x4*)(Ks[0] + (qh * 32 + l32) * 136 + kh * 64 + mt * 32 + rq * 8 +
                lh * 4) = pk;
    }
  __syncthreads();
#pragma unroll
  for (int i = 0; i < 4; i++) {
    const int c = i * 256 + tid;
    const int row = c >> 4, ch = c & 15;
    const u16x8 vv = *(const u16x8*)(Ks[0] + row * 136 + ch * 8);
    *(u16x8*)(o + (size_t)(q0 + row) * DMODEL + h * HD + ch * 8) = vv;
  }
}

// ---------------- launcher ----------------
extern "C" void kernel_launch(void* const* d_in, const int* in_sizes, int n_in,
                              void* d_out, int out_size, void* d_ws, size_t ws_size,
                              hipStream_t stream) {
  (void)in_sizes; (void)n_in; (void)out_size; (void)ws_size;
  const float* x  = (const float*)d_in[0];
  const float* wq = (const float*)d_in[1];
  const float* wk = (const float*)d_in[2];
  const float* wv = (const float*)d_in[3];
  const float* wo = (const float*)d_in[4];
  float* out = (float*)d_out;

  const size_t NE = (size_t)S_LEN * DMODEL;
  unsigned short* ws = (unsigned short*)d_ws;
  unsigned short* xb  = ws + 0 * NE;
  unsigned short* wqb = ws + 1 * NE;
  unsigned short* wkb = ws + 2 * NE;
  unsigned short* wvb = ws + 3 * NE;
  unsigned short* wob = ws + 4 * NE;
  unsigned short* qb  = ws + 5 * NE;
  unsigned short* kb  = ws + 6 * NE;
  unsigned short* vTb = ws + 7 * NE;
  unsigned short* ob  = ws + 8 * NE;

  const float qscale = 0.08838834764831845f * 1.4426950408889634f;

  cast_all<<<dim3(5 * 4096), dim3(256), 0, stream>>>(x, wq, wk, wv, wo, ws,
                                                     qscale);

  gemm_qkv<<<dim3(48, 16), dim3(256), 0, stream>>>(xb, wqb, wkb, wvb, qb, kb,
                                                   vTb);

  attn_kernel<<<dim3(S_LEN / 64, NHEADS), dim3(256), 0, stream>>>(qb, kb, vTb,
                                                                  ob);

  gemm_bt64<<<dim3(16, 32), dim3(256), 0, stream>>>(ob, wob, out, S_LEN,
                                                    DMODEL, DMODEL);
}